// Round 1
// baseline (60.240 us; speedup 1.0000x reference)
//
#include <hip/hip_runtime.h>

#define M_DIM 64
#define K_DIM 8192
#define N_DIM 8192
#define QB 32
#define NT 64               // N columns per block
#define KC 64               // K per stage (2 quant blocks)
#define SPLITS 4
#define KSPLIT (K_DIM / SPLITS)    // 2048
#define NSTAGE (KSPLIT / KC)       // 32

typedef __attribute__((ext_vector_type(8))) short short8;     // 8 bf16 (4 VGPRs) - MFMA A/B frag
typedef __attribute__((ext_vector_type(8))) unsigned short ushort8;
typedef __attribute__((ext_vector_type(4))) float f32x4;

static_assert(NSTAGE * KC == KSPLIT, "split must tile");

// f32 -> bf16 round-to-nearest-even (no NaN inputs here)
__device__ __forceinline__ unsigned short f2bf(float f) {
    unsigned u = __builtin_bit_cast(unsigned, f);
    u += 0x7fffu + ((u >> 16) & 1u);
    return (unsigned short)(u >> 16);
}

// Rewrites the whole output with bias every call (d_out is poisoned once and
// never re-poisoned between replays; main kernel atomicAdds on top of this).
__global__ __launch_bounds__(256) void bias_init(const float* __restrict__ bias,
                                                 float* __restrict__ out) {
    int i = (blockIdx.x * 256 + threadIdx.x) * 4;
    int n = i & (N_DIM - 1);
    *(f32x4*)(out + i) = *(const f32x4*)(bias + n);
}

__global__ __launch_bounds__(256, 2) void qgemm(
    const float* __restrict__ x,       // [M][K]
    const float* __restrict__ scales,  // [K/QB][N]
    const float* __restrict__ zeros,   // [K/QB][N]
    const int*   __restrict__ qw,      // [K][N], values 0..255
    float*       __restrict__ out)     // [M][N]
{
    // Transposed weight tile [n][k] and x tile [m][k], bf16, double-buffered.
    // Row stride 72 elems = 144 B: multiple of 16 B (b128-aligned reads),
    // 36 banks/row => adequately spread for b128 reads, b64 writes ~2-way.
    __shared__ unsigned short lq[2][NT][72];
    __shared__ unsigned short lx[2][M_DIM][72];

    const int tid  = threadIdx.x;
    const int lane = tid & 63;
    const int w    = tid >> 6;          // wave 0..3, owns cols [16w,16w+16)

    const int n0 = blockIdx.x * NT;
    const int k0 = blockIdx.y * KSPLIT;

    const int qn   = n0 + lane;         // this thread's weight column
    const int xrow = tid >> 2;          // x staging: row 0..63
    const int xcol = (tid & 3) * 16;    // 16 k's per thread

    // stage registers
    int   qv[16];                       // 4 sets x 4 adjacent k, one column
    float sv0, sv1, zv0, zv1;
    f32x4 xv[4];

    auto load_stage = [&](int kk) {
        // weights: set s, elem j -> row kk+16s+4w+j, col qn.
        // Per wave per instr: 64 consecutive dwords (256B) -> fully coalesced.
        #pragma unroll
        for (int s = 0; s < 4; ++s)
            #pragma unroll
            for (int j = 0; j < 4; ++j)
                qv[s * 4 + j] = qw[(size_t)(kk + 16 * s + 4 * w + j) * N_DIM + qn];
        const int b0 = kk >> 5;
        sv0 = scales[(size_t)b0 * N_DIM + qn];
        sv1 = scales[(size_t)(b0 + 1) * N_DIM + qn];
        zv0 = zeros[(size_t)b0 * N_DIM + qn];
        zv1 = zeros[(size_t)(b0 + 1) * N_DIM + qn];
        #pragma unroll
        for (int i = 0; i < 4; ++i)
            xv[i] = *(const f32x4*)(x + (size_t)xrow * K_DIM + kk + xcol + 4 * i);
    };

    load_stage(k0);

    f32x4 acc[4];
    #pragma unroll
    for (int r = 0; r < 4; ++r) acc[r] = (f32x4){0.f, 0.f, 0.f, 0.f};

    for (int t = 0; t < NSTAGE; ++t) {
        const int cur = t & 1;

        // --- dequant stage-t regs -> packed bf16 ---
        const float nz0 = -sv0 * zv0, nz1 = -sv1 * zv1;
        const float s0r = sv0, s1r = sv1;
        uint2 qd[4];
        #pragma unroll
        for (int s = 0; s < 4; ++s) {
            const float sc = (s < 2) ? s0r : s1r;
            const float nz = (s < 2) ? nz0 : nz1;
            unsigned short h0 = f2bf(fmaf((float)qv[s * 4 + 0], sc, nz));
            unsigned short h1 = f2bf(fmaf((float)qv[s * 4 + 1], sc, nz));
            unsigned short h2 = f2bf(fmaf((float)qv[s * 4 + 2], sc, nz));
            unsigned short h3 = f2bf(fmaf((float)qv[s * 4 + 3], sc, nz));
            qd[s].x = (unsigned)h0 | ((unsigned)h1 << 16);
            qd[s].y = (unsigned)h2 | ((unsigned)h3 << 16);
        }
        ushort8 xw0, xw1;
        #pragma unroll
        for (int e = 0; e < 4; ++e) {
            xw0[e]     = f2bf(xv[0][e]);
            xw0[4 + e] = f2bf(xv[1][e]);
            xw1[e]     = f2bf(xv[2][e]);
            xw1[4 + e] = f2bf(xv[3][e]);
        }

        // --- issue loads for stage t+1 (in flight across the barrier) ---
        if (t + 1 < NSTAGE) load_stage(k0 + (t + 1) * KC);

        // --- stage to LDS (transposed [n][k] for B, [m][k] for A) ---
        #pragma unroll
        for (int s = 0; s < 4; ++s)
            *(uint2*)&lq[cur][lane][16 * s + 4 * w] = qd[s];
        *(ushort8*)&lx[cur][xrow][xcol]     = xw0;
        *(ushort8*)&lx[cur][xrow][xcol + 8] = xw1;

        __syncthreads();

        // --- MFMA: wave w = cols [16w,16w+16), all 64 rows, K step 32 ---
        #pragma unroll
        for (int c = 0; c < 2; ++c) {
            const short8 bf = *(const short8*)&lq[cur][16 * w + (lane & 15)]
                                                [32 * c + 8 * (lane >> 4)];
            #pragma unroll
            for (int r = 0; r < 4; ++r) {
                const short8 af = *(const short8*)&lx[cur][16 * r + (lane & 15)]
                                                    [32 * c + 8 * (lane >> 4)];
                acc[r] = __builtin_amdgcn_mfma_f32_16x16x32_bf16(af, bf, acc[r], 0, 0, 0);
            }
        }
    }

    // --- epilogue: C layout col=lane&15, row=4*(lane>>4)+e (verified m89) ---
    const int cn = n0 + 16 * w + (lane & 15);
    #pragma unroll
    for (int r = 0; r < 4; ++r) {
        const int m = 16 * r + 4 * (lane >> 4);
        #pragma unroll
        for (int e = 0; e < 4; ++e)
            atomicAdd(out + (size_t)(m + e) * N_DIM + cn, acc[r][e]);
    }
}

extern "C" void kernel_launch(void* const* d_in, const int* in_sizes, int n_in,
                              void* d_out, int out_size, void* d_ws, size_t ws_size,
                              hipStream_t stream) {
    const float* x      = (const float*)d_in[0];
    const float* scales = (const float*)d_in[1];
    const float* zeros  = (const float*)d_in[2];
    const float* bias   = (const float*)d_in[3];
    const int*   qw     = (const int*)d_in[4];
    float* out = (float*)d_out;

    bias_init<<<dim3((M_DIM * N_DIM) / 1024), 256, 0, stream>>>(bias, out);
    qgemm<<<dim3(N_DIM / NT, SPLITS), 256, 0, stream>>>(x, scales, zeros, qw, out);
}